// Round 10
// baseline (904.865 us; speedup 1.0000x reference)
//
#include <hip/hip_runtime.h>
#include <hip/hip_fp16.h>

// ===== INSTRUMENTATION BUILD =====
// R6 kernels byte-identical, but each repeats its work in-kernel so every
// dispatch exceeds the ~170us fillBuffer floor and shows up in rocprof top-5.
// k1/k3: idempotent re-execution. k2/k4: reps 0..N-2 hit a shadow buffer
// (same contention pattern), only the last rep hits the real target.
#define R1REP 4
#define R2REP 16
#define R3REP 64
#define R4REP 16

#define N_NODES  50000
#define N_EDGES  300000
#define IN_FEATS 1433
#define HIDDEN   16
#define OUT_F    7
#define KPAD     1472   // 23*64, zero-padded K extent for W1 in LDS
#define WROW     9      // dwords per W1 row; stride 9 (odd) -> 2 lanes/bank = free

// ---------- Kernel 1: H = F @ W1 (fp16 W in LDS); aggbuf = H + b1 ----------
__global__ __launch_bounds__(256) void k1_probe(
    const float* __restrict__ F, const float* __restrict__ W1,
    const float* __restrict__ b1, __half* __restrict__ H,
    __half* __restrict__ aggbuf)
{
    __shared__ unsigned int Wl[KPAD * WROW];   // 52,992 B -> 3 blocks/CU
    const int tid = threadIdx.x;

    for (int idx = tid; idx < KPAD * 8; idx += 256) {
        int k = idx >> 3, c = idx & 7;
        unsigned int u = 0u;
        if (k < IN_FEATS) {
            __half2 h2 = __floats2half2_rn(W1[k * 16 + 2 * c], W1[k * 16 + 2 * c + 1]);
            u = *reinterpret_cast<unsigned int*>(&h2);
        }
        Wl[k * WROW + c] = u;
    }
    __syncthreads();

    const int lane = tid & 63;
    const float b1v = b1[lane & 15];
    const int gwave  = blockIdx.x * 4 + (tid >> 6);
    const int nwaves = gridDim.x * 4;

    for (int rep = 0; rep < R1REP; ++rep) {
        for (int ch = gwave; ch < N_NODES / 4; ch += nwaves) {
            const int r0 = ch * 4;
            const float* fp = F + (size_t)r0 * IN_FEATS;

            float v[64];                                // acc[idx = r*16 + j]
            #pragma unroll
            for (int i = 0; i < 64; ++i) v[i] = 0.f;

            #pragma unroll 2
            for (int i = 0; i < 22; ++i) {      // k < 1408: no bounds check
                const int k = i * 64 + lane;
                const float f0 = fp[k];
                const float f1 = fp[IN_FEATS + k];
                const float f2 = fp[2 * IN_FEATS + k];
                const float f3 = fp[3 * IN_FEATS + k];
                float wv[16];
                #pragma unroll
                for (int c = 0; c < 8; ++c) {
                    unsigned int u = Wl[k * WROW + c];
                    __half2 h2 = *reinterpret_cast<__half2*>(&u);
                    float2 f = __half22float2(h2);
                    wv[2 * c]     = f.x;
                    wv[2 * c + 1] = f.y;
                }
                #pragma unroll
                for (int j = 0; j < 16; ++j) {
                    v[j]      += f0 * wv[j];
                    v[16 + j] += f1 * wv[j];
                    v[32 + j] += f2 * wv[j];
                    v[48 + j] += f3 * wv[j];
                }
            }
            {   // masked tail: k = 1408 + lane
                const int k = 1408 + lane;
                float f0 = 0.f, f1 = 0.f, f2 = 0.f, f3 = 0.f;
                if (k < IN_FEATS) {
                    f0 = fp[k];
                    f1 = fp[IN_FEATS + k];
                    f2 = fp[2 * IN_FEATS + k];
                    f3 = fp[3 * IN_FEATS + k];
                }
                float wv[16];
                #pragma unroll
                for (int c = 0; c < 8; ++c) {
                    unsigned int u = Wl[k * WROW + c];
                    __half2 h2 = *reinterpret_cast<__half2*>(&u);
                    float2 f = __half22float2(h2);
                    wv[2 * c]     = f.x;
                    wv[2 * c + 1] = f.y;
                }
                #pragma unroll
                for (int j = 0; j < 16; ++j) {
                    v[j]      += f0 * wv[j];
                    v[16 + j] += f1 * wv[j];
                    v[32 + j] += f2 * wv[j];
                    v[48 + j] += f3 * wv[j];
                }
            }

            #pragma unroll
            for (int d = 5; d >= 0; --d) {
                const int half = 1 << d;
                const bool hi = (lane >> d) & 1;
                #pragma unroll
                for (int t = 0; t < (1 << d); ++t) {
                    float sent = hi ? v[t] : v[t + half];
                    float recv = __shfl_xor(sent, half, 64);
                    float keep = hi ? v[t + half] : v[t];
                    v[t] = keep + recv;
                }
            }
            const size_t off = (size_t)r0 * 16 + lane;
            H[off]      = __float2half(v[0]);
            aggbuf[off] = __float2half(v[0] + b1v);
        }
    }
}

// ---------- Kernel 2: aggbuf[dst] += H[src], packed-fp16 atomics ----------
__global__ __launch_bounds__(256) void k2_probe(
    const int* __restrict__ src, const int* __restrict__ dst,
    const __half2* __restrict__ H2, __half2* __restrict__ agg2,
    __half2* __restrict__ shadow2)
{
    int t = blockIdx.x * 256 + threadIdx.x;     // grid sized exactly N_EDGES*8
    int e = t >> 3, p = t & 7;
    int s = src[e], d = dst[e];
    __half2 val = H2[(size_t)s * 8 + p];
    for (int rep = 0; rep < R2REP; ++rep) {
        __half2* tgt = (rep == R2REP - 1) ? agg2 : shadow2;
        unsafeAtomicAdd(&tgt[(size_t)d * 8 + p], val);
    }
}

// ---------- Kernel 3: x = relu(aggbuf fp16); G = x @ W2; out = G + b2 ----------
__global__ __launch_bounds__(256) void k3_probe(
    const __half2* __restrict__ agg2, const float* __restrict__ W2,
    const float* __restrict__ b2, float* __restrict__ G,
    float* __restrict__ out)
{
    int n0 = blockIdx.x * 256 + threadIdx.x;
    if (n0 >= N_NODES) return;
    for (int rep = 0; rep < R3REP; ++rep) {
        int n = n0;
        asm volatile("" : "+v"(n));   // opaque: force full re-execution per rep
        float x[16];
        #pragma unroll
        for (int p = 0; p < 8; ++p) {
            float2 f = __half22float2(agg2[(size_t)n * 8 + p]);
            x[2 * p]     = f.x > 0.f ? f.x : 0.f;
            x[2 * p + 1] = f.y > 0.f ? f.y : 0.f;
        }
        #pragma unroll
        for (int j = 0; j < OUT_F; ++j) {
            float g = 0.f;
            #pragma unroll
            for (int k = 0; k < 16; ++k) g += x[k] * W2[k * OUT_F + j];
            G[(size_t)n * OUT_F + j] = g;
            out[(size_t)n * OUT_F + j] = g + b2[j];
        }
    }
}

// ---------- Kernel 4: out[dst] += G[src], f32 atomics ----------
__global__ __launch_bounds__(256) void k4_probe(
    const int* __restrict__ src, const int* __restrict__ dst,
    const float* __restrict__ G, float* __restrict__ out,
    float* __restrict__ shadowOut)
{
    int t = blockIdx.x * 256 + threadIdx.x;
    int e = t / OUT_F, j = t % OUT_F;
    if (e < N_EDGES) {
        float val = G[(size_t)src[e] * OUT_F + j];
        size_t off = (size_t)dst[e] * OUT_F + j;
        for (int rep = 0; rep < R4REP; ++rep) {
            float* tgt = (rep == R4REP - 1) ? out : shadowOut;
            atomicAdd(&tgt[off], val);
        }
    }
}

extern "C" void kernel_launch(void* const* d_in, const int* in_sizes, int n_in,
                              void* d_out, int out_size, void* d_ws, size_t ws_size,
                              hipStream_t stream)
{
    const float* F   = (const float*)d_in[0];
    const int*   src = (const int*)d_in[1];
    const int*   dst = (const int*)d_in[2];
    const float* W1  = (const float*)d_in[3];
    const float* b1  = (const float*)d_in[4];
    const float* W2  = (const float*)d_in[5];
    const float* b2  = (const float*)d_in[6];
    float* out = (float*)d_out;

    __half* H       = (__half*)d_ws;                        // 800,000 fp16
    __half* aggbuf  = H + (size_t)N_NODES * HIDDEN;         // 800,000 fp16
    float*  G       = (float*)(aggbuf + (size_t)N_NODES * HIDDEN);   // 350,000 f32
    __half* shadowA = (__half*)(G + (size_t)N_NODES * OUT_F);        // 800,000 fp16
    float*  shadowO = (float*)(shadowA + (size_t)N_NODES * HIDDEN);  // 350,000 f32

    k1_probe<<<768, 256, 0, stream>>>(F, W1, b1, H, aggbuf);
    k2_probe<<<(N_EDGES * 8) / 256, 256, 0, stream>>>(src, dst,
        (const __half2*)H, (__half2*)aggbuf, (__half2*)shadowA);
    k3_probe<<<(N_NODES + 255) / 256, 256, 0, stream>>>((const __half2*)aggbuf,
        W2, b2, G, out);
    k4_probe<<<(N_EDGES * OUT_F + 255) / 256, 256, 0, stream>>>(src, dst, G, out,
        shadowO);
}

// Round 11
// 116.886 us; speedup vs baseline: 7.7415x; 7.7415x over previous
//
#include <hip/hip_runtime.h>
#include <hip/hip_fp16.h>

#define N_NODES  50000
#define N_EDGES  300000
#define IN_FEATS 1433
#define HIDDEN   16
#define OUT_F    7
#define KPAD     1472   // zero-padded K extent for packed W

// ---------- Kernel 0: pack W1 (1433x16 f32) -> Wp (1472x16 fp16, zero-padded) ----------
__global__ __launch_bounds__(256) void k0_pack(
    const float* __restrict__ W1, __half* __restrict__ Wp)
{
    int idx = blockIdx.x * 256 + threadIdx.x;       // grid covers KPAD*16 exactly
    int k = idx >> 4, c = idx & 15;
    float v = (k < IN_FEATS) ? W1[k * 16 + c] : 0.f;
    Wp[idx] = __float2half(v);
}

// ---------- Kernel 1: H = F @ W1; aggbuf = H + b1 ----------
// No LDS: W read from L2-resident packed-fp16 Wp, coalesced 32B/lane
// (lane reads row k=64i+lane -> consecutive lanes, consecutive rows).
// Occupancy now VGPR-bound (~16-20 waves/CU vs 12 LDS-capped) and W-loads
// pipeline in vmcnt alongside F-loads -> latency actually hidden.
// 3125 blocks x 4 waves = 12500 waves = exactly one 4-row chunk per wave.
__global__ __launch_bounds__(256) void k1_gemm(
    const float* __restrict__ F, const __half* __restrict__ Wp,
    const float* __restrict__ b1, __half* __restrict__ H,
    __half* __restrict__ aggbuf)
{
    const int tid  = threadIdx.x;
    const int lane = tid & 63;
    const float b1v = b1[lane & 15];
    const int ch = blockIdx.x * 4 + (tid >> 6);     // 0..12499, one chunk per wave

    const int r0 = ch * 4;
    const float* fp = F + (size_t)r0 * IN_FEATS;

    float v[64];                                    // acc[idx = r*16 + j]
    #pragma unroll
    for (int i = 0; i < 64; ++i) v[i] = 0.f;

    #pragma unroll 2
    for (int i = 0; i < 22; ++i) {                  // k < 1408: no bounds check
        const int k = i * 64 + lane;
        const float f0 = fp[k];
        const float f1 = fp[IN_FEATS + k];
        const float f2 = fp[2 * IN_FEATS + k];
        const float f3 = fp[3 * IN_FEATS + k];
        // W row k: 16 fp16 = 32B, 16B-aligned, coalesced across lanes
        const uint4* wrow = reinterpret_cast<const uint4*>(Wp + (size_t)k * 16);
        const uint4 wa = wrow[0];
        const uint4 wb = wrow[1];
        float wv[16];
        {
            float2 t;
            t = __half22float2(*(const __half2*)&wa.x); wv[0]=t.x;  wv[1]=t.y;
            t = __half22float2(*(const __half2*)&wa.y); wv[2]=t.x;  wv[3]=t.y;
            t = __half22float2(*(const __half2*)&wa.z); wv[4]=t.x;  wv[5]=t.y;
            t = __half22float2(*(const __half2*)&wa.w); wv[6]=t.x;  wv[7]=t.y;
            t = __half22float2(*(const __half2*)&wb.x); wv[8]=t.x;  wv[9]=t.y;
            t = __half22float2(*(const __half2*)&wb.y); wv[10]=t.x; wv[11]=t.y;
            t = __half22float2(*(const __half2*)&wb.z); wv[12]=t.x; wv[13]=t.y;
            t = __half22float2(*(const __half2*)&wb.w); wv[14]=t.x; wv[15]=t.y;
        }
        #pragma unroll
        for (int j = 0; j < 16; ++j) {
            v[j]      += f0 * wv[j];
            v[16 + j] += f1 * wv[j];
            v[32 + j] += f2 * wv[j];
            v[48 + j] += f3 * wv[j];
        }
    }
    {   // masked tail: k = 1408 + lane (Wp rows zero-padded to 1472)
        const int k = 1408 + lane;
        float f0 = 0.f, f1 = 0.f, f2 = 0.f, f3 = 0.f;
        if (k < IN_FEATS) {
            f0 = fp[k];
            f1 = fp[IN_FEATS + k];
            f2 = fp[2 * IN_FEATS + k];
            f3 = fp[3 * IN_FEATS + k];
        }
        const uint4* wrow = reinterpret_cast<const uint4*>(Wp + (size_t)k * 16);
        const uint4 wa = wrow[0];
        const uint4 wb = wrow[1];
        float wv[16];
        {
            float2 t;
            t = __half22float2(*(const __half2*)&wa.x); wv[0]=t.x;  wv[1]=t.y;
            t = __half22float2(*(const __half2*)&wa.y); wv[2]=t.x;  wv[3]=t.y;
            t = __half22float2(*(const __half2*)&wa.z); wv[4]=t.x;  wv[5]=t.y;
            t = __half22float2(*(const __half2*)&wa.w); wv[6]=t.x;  wv[7]=t.y;
            t = __half22float2(*(const __half2*)&wb.x); wv[8]=t.x;  wv[9]=t.y;
            t = __half22float2(*(const __half2*)&wb.y); wv[10]=t.x; wv[11]=t.y;
            t = __half22float2(*(const __half2*)&wb.z); wv[12]=t.x; wv[13]=t.y;
            t = __half22float2(*(const __half2*)&wb.w); wv[14]=t.x; wv[15]=t.y;
        }
        #pragma unroll
        for (int j = 0; j < 16; ++j) {
            v[j]      += f0 * wv[j];
            v[16 + j] += f1 * wv[j];
            v[32 + j] += f2 * wv[j];
            v[48 + j] += f3 * wv[j];
        }
    }

    // Halving butterfly: lane l ends with v[0] = full K-sum of idx = l
    #pragma unroll
    for (int d = 5; d >= 0; --d) {
        const int half = 1 << d;
        const bool hi = (lane >> d) & 1;
        #pragma unroll
        for (int t = 0; t < (1 << d); ++t) {
            float sent = hi ? v[t] : v[t + half];
            float recv = __shfl_xor(sent, half, 64);
            float keep = hi ? v[t + half] : v[t];
            v[t] = keep + recv;
        }
    }
    const size_t off = (size_t)r0 * 16 + lane;
    H[off]      = __float2half(v[0]);
    aggbuf[off] = __float2half(v[0] + b1v);
}

// ---------- Kernel 2: aggbuf[dst] += H[src], packed-fp16 atomics ----------
__global__ __launch_bounds__(256) void k2_scatter1(
    const int* __restrict__ src, const int* __restrict__ dst,
    const __half2* __restrict__ H2, __half2* __restrict__ agg2)
{
    int t = blockIdx.x * 256 + threadIdx.x;     // grid sized exactly N_EDGES*8
    int e = t >> 3, p = t & 7;
    int s = src[e], d = dst[e];
    __half2 val = H2[(size_t)s * 8 + p];
    unsafeAtomicAdd(&agg2[(size_t)d * 8 + p], val);   // global_atomic_pk_add_f16
}

// ---------- Kernel 3: x = relu(aggbuf fp16); G = x @ W2; out = G + b2 ----------
__global__ __launch_bounds__(256) void k3_layer2(
    const __half2* __restrict__ agg2, const float* __restrict__ W2,
    const float* __restrict__ b2, float* __restrict__ G,
    float* __restrict__ out)
{
    int n = blockIdx.x * 256 + threadIdx.x;
    if (n >= N_NODES) return;
    float x[16];
    #pragma unroll
    for (int p = 0; p < 8; ++p) {
        float2 f = __half22float2(agg2[(size_t)n * 8 + p]);
        x[2 * p]     = f.x > 0.f ? f.x : 0.f;
        x[2 * p + 1] = f.y > 0.f ? f.y : 0.f;
    }
    #pragma unroll
    for (int j = 0; j < OUT_F; ++j) {
        float g = 0.f;
        #pragma unroll
        for (int k = 0; k < 16; ++k) g += x[k] * W2[k * OUT_F + j];
        G[(size_t)n * OUT_F + j] = g;
        out[(size_t)n * OUT_F + j] = g + b2[j];
    }
}

// ---------- Kernel 4: out[dst] += G[src], relaxed-scope f32 atomics ----------
// R10 probe: device-scope atomicAdd write-throughs to HBM (274MB for 33.6M ops,
// 86 G/s); unsafeAtomicAdd stays in L2 like k2's pk-fp16 (343 G/s).
__global__ __launch_bounds__(256) void k4_scatter2(
    const int* __restrict__ src, const int* __restrict__ dst,
    const float* __restrict__ G, float* __restrict__ out)
{
    int t = blockIdx.x * 256 + threadIdx.x;
    int e = t / OUT_F, j = t % OUT_F;
    if (e < N_EDGES) {
        unsafeAtomicAdd(&out[(size_t)dst[e] * OUT_F + j],
                        G[(size_t)src[e] * OUT_F + j]);
    }
}

extern "C" void kernel_launch(void* const* d_in, const int* in_sizes, int n_in,
                              void* d_out, int out_size, void* d_ws, size_t ws_size,
                              hipStream_t stream)
{
    const float* F   = (const float*)d_in[0];
    const int*   src = (const int*)d_in[1];
    const int*   dst = (const int*)d_in[2];
    const float* W1  = (const float*)d_in[3];
    const float* b1  = (const float*)d_in[4];
    const float* W2  = (const float*)d_in[5];
    const float* b2  = (const float*)d_in[6];
    float* out = (float*)d_out;

    __half* H      = (__half*)d_ws;                         // 800,000 fp16
    __half* aggbuf = H + (size_t)N_NODES * HIDDEN;          // 800,000 fp16
    float*  G      = (float*)(aggbuf + (size_t)N_NODES * HIDDEN);  // 350,000 f32
    __half* Wp     = (__half*)(G + (size_t)N_NODES * OUT_F);       // 23,552 fp16

    k0_pack<<<(KPAD * 16) / 256, 256, 0, stream>>>(W1, Wp);
    // 3125 blocks x 256 thr: exactly one 4-row chunk per wave, no LDS
    k1_gemm<<<N_NODES / 16, 256, 0, stream>>>(F, Wp, b1, H, aggbuf);
    k2_scatter1<<<(N_EDGES * 8) / 256, 256, 0, stream>>>(src, dst,
        (const __half2*)H, (__half2*)aggbuf);
    k3_layer2<<<(N_NODES + 255) / 256, 256, 0, stream>>>((const __half2*)aggbuf,
        W2, b2, G, out);
    k4_scatter2<<<(N_EDGES * OUT_F + 255) / 256, 256, 0, stream>>>(src, dst, G, out);
}